// Round 3
// baseline (281.057 us; speedup 1.0000x reference)
//
#include <hip/hip_runtime.h>
#include <math.h>

// ---------------- problem constants ----------------
#define N        2048
#define NT       256      // threads per block
#define NSC      81       // number of scales (J+1)
#define BATCH    64
#define WS_WIN   94       // sliding window = 32*3-2
#define NOUT     1955     // N - WS_WIN + 1
#define DT_S     0.1f
#define W0_C     6.0f
#define PI_F     3.14159265358979f
#define TWOPI_F  6.28318530717959f
#define PIM14    0.7511255444649425f   // pi^(-1/4)
#define C_SQ2H   0.70710678118654752f  // sqrt(2)/2

// pad-swizzle: +1 element every 16 keeps every stage's b64 pattern at the
// 4-lane/bank-pair bandwidth floor (verified per-stage in journal)
#define SWZ(e)   ((e) + ((e) >> 4))
#define LDSN     2176     // 2048 + 128 pad elements

__device__ __forceinline__ float2 cadd2(float2 a, float2 b) { return make_float2(a.x + b.x, a.y + b.y); }
__device__ __forceinline__ float2 csub2(float2 a, float2 b) { return make_float2(a.x - b.x, a.y - b.y); }
__device__ __forceinline__ float2 cmul2(float2 a, float2 b) { return make_float2(a.x * b.x - a.y * b.y, a.x * b.y + a.y * b.x); }

// 8-point DFT, natural-order outputs (sign SGN), same math as verified R1 stage8
template<int SGN>
__device__ __forceinline__ void dft8(const float2 (&x)[8], float2 (&y)[8]) {
    const float s = (float)SGN;
    float2 t0 = cadd2(x[0], x[4]), t1 = cadd2(x[1], x[5]);
    float2 t2 = cadd2(x[2], x[6]), t3 = cadd2(x[3], x[7]);
    float2 u0 = csub2(x[0], x[4]);
    float2 d1 = csub2(x[1], x[5]);
    float2 d2 = csub2(x[2], x[6]);
    float2 d3 = csub2(x[3], x[7]);
    float2 u1 = make_float2(C_SQ2H * (d1.x - s * d1.y), C_SQ2H * (d1.y + s * d1.x));
    float2 u2 = make_float2(-s * d2.y, s * d2.x);
    float2 u3 = make_float2(-C_SQ2H * (d3.x + s * d3.y), C_SQ2H * (s * d3.x - d3.y));
    float2 a0 = cadd2(t0, t2), a1 = cadd2(t1, t3), b0 = csub2(t0, t2), e1 = csub2(t1, t3);
    float2 b1 = make_float2(-s * e1.y, s * e1.x);
    y[0] = cadd2(a0, a1); y[4] = csub2(a0, a1); y[2] = cadd2(b0, b1); y[6] = csub2(b0, b1);
    float2 c0 = cadd2(u0, u2), c1 = cadd2(u1, u3), g0 = csub2(u0, u2), h1 = csub2(u1, u3);
    float2 g1 = make_float2(-s * h1.y, s * h1.x);
    y[1] = cadd2(c0, c1); y[5] = csub2(c0, c1); y[3] = cadd2(g0, g1); y[7] = csub2(g0, g1);
}

// twiddle by w^u (w = exp(SGN*2pi*i*jm/N)) and scatter-store
template<int SGN>
__device__ __forceinline__ void twiddle_store(const float2 (&y)[8], float2* __restrict__ dst,
                                              int jm, int base, int m) {
    float ang = (float)SGN * (TWOPI_F / (float)N) * (float)jm;
    float sn, cs; __sincosf(ang, &sn, &cs);
    float2 w1 = make_float2(cs, sn);
    float2 w2 = cmul2(w1, w1);
    float2 w3 = cmul2(w2, w1);
    float2 w4 = cmul2(w2, w2);
    float2 w5 = cmul2(w3, w2);
    float2 w6 = cmul2(w3, w3);
    float2 w7 = cmul2(w4, w3);
    dst[SWZ(base)]         = y[0];
    dst[SWZ(base + m)]     = cmul2(y[1], w1);
    dst[SWZ(base + 2 * m)] = cmul2(y[2], w2);
    dst[SWZ(base + 3 * m)] = cmul2(y[3], w3);
    dst[SWZ(base + 4 * m)] = cmul2(y[4], w4);
    dst[SWZ(base + 5 * m)] = cmul2(y[5], w5);
    dst[SWZ(base + 6 * m)] = cmul2(y[6], w6);
    dst[SWZ(base + 7 * m)] = cmul2(y[7], w7);
}

// stage 1 (m=1): input from registers x[p] = element tid + p*256
template<int SGN>
__device__ __forceinline__ void stage1_reg(const float2 (&x)[8], float2* __restrict__ dst, int tid) {
    float2 y[8];
    dft8<SGN>(x, y);
    twiddle_store<SGN>(y, dst, tid, 8 * tid, 1);
}

// middle radix-8 stage, LDS -> LDS
template<int SGN>
__device__ __forceinline__ void stage8_lds(const float2* __restrict__ src,
                                           float2* __restrict__ dst, int q, int shift) {
    float2 xin[8];
    #pragma unroll
    for (int p = 0; p < 8; ++p) xin[p] = src[SWZ(q + p * 256)];
    float2 y[8];
    dft8<SGN>(xin, y);
    const int m  = 1 << shift;
    const int jm = q & ~(m - 1);
    twiddle_store<SGN>(y, dst, jm, q + 7 * jm, m);
}

// final radix-4 stage (m=512, j=0, no twiddles): outputs land back in regs,
// x[2u+qq] = element tid + (2u+qq)*256  (natural order, thread-owned)
template<int SGN>
__device__ __forceinline__ void stage4_regs(const float2* __restrict__ src, float2 (&x)[8], int tid) {
    const float s = (float)SGN;
    #pragma unroll
    for (int qq = 0; qq < 2; ++qq) {
        int q = tid + qq * 256;
        float2 x0 = src[SWZ(q)];
        float2 x1 = src[SWZ(q + 512)];
        float2 x2 = src[SWZ(q + 1024)];
        float2 x3 = src[SWZ(q + 1536)];
        float2 a0 = cadd2(x0, x2), a1 = cadd2(x1, x3);
        float2 b0 = csub2(x0, x2), e1 = csub2(x1, x3);
        float2 b1 = make_float2(-s * e1.y, s * e1.x);
        x[0 + qq] = cadd2(a0, a1);
        x[2 + qq] = cadd2(b0, b1);
        x[4 + qq] = csub2(a0, a1);
        x[6 + qq] = csub2(b0, b1);
    }
}

// full 2048-pt FFT, register in / register out (x[i] = element tid + i*256).
// SGN=-1: forward (numpy fft). SGN=+1: inverse exponent (1/N not applied).
template<int SGN>
__device__ __forceinline__ void fft2048_reg(float2 (&x)[8], float2* A, float2* B, int tid) {
    __syncthreads();                     // protect B from previous FFT's reads
    stage1_reg<SGN>(x, B, tid);          // regs -> B   (m=1)
    __syncthreads();
    stage8_lds<SGN>(B, A, tid, 3);       // B -> A      (m=8)
    __syncthreads();
    stage8_lds<SGN>(A, B, tid, 6);       // A -> B      (m=64)
    __syncthreads();
    stage4_regs<SGN>(B, x, tid);         // B -> regs   (m=512)
}

// ---------------- K1: normalize + forward FFT of each signal ----------------
__global__ __launch_bounds__(NT) void k_fft_in(const float* __restrict__ x,
                                               float2* __restrict__ spec) {
    __shared__ float2 A[LDSN];
    __shared__ float2 B[LDSN];
    __shared__ float  rs[NT], rq[NT];
    const int    tid = threadIdx.x;
    const float* y   = x + (size_t)blockIdx.x * N;

    float v[8];
    float lsum = 0.f, lsq = 0.f;
    #pragma unroll
    for (int i = 0; i < 8; ++i) {
        float t = y[tid + i * NT];
        v[i] = t; lsum += t; lsq += t * t;
    }
    rs[tid] = lsum; rq[tid] = lsq;
    __syncthreads();
    for (int o = NT / 2; o > 0; o >>= 1) {
        if (tid < o) { rs[tid] += rs[tid + o]; rq[tid] += rq[tid + o]; }
        __syncthreads();
    }
    const float mean = rs[0] * (1.f / N);
    const float var  = rq[0] * (1.f / N) - mean * mean;
    const float inv  = rsqrtf(var);

    float2 z[8];
    #pragma unroll
    for (int i = 0; i < 8; ++i) z[i] = make_float2((v[i] - mean) * inv, 0.f);

    fft2048_reg<-1>(z, A, B, tid);

    float2* o2 = spec + (size_t)blockIdx.x * N;
    #pragma unroll
    for (int i = 0; i < 8; ++i) o2[tid + i * NT] = z[i];
}

// ---------------- K2: per (batch, scale) CWT + smoothing ----------------
__global__ __launch_bounds__(NT, 4) void k_wct(const float2* __restrict__ spec,
                                               float4* __restrict__ T, int b0) {
    __shared__ float2 A[LDSN];
    __shared__ float2 B[LDSN];
    const int tid  = threadIdx.x;
    const int sidx = blockIdx.x % NSC;
    const int bl   = blockIdx.x / NSC;
    const int b    = b0 + bl;

    const float s0    = 2.f * DT_S * (W0_C + sqrtf(2.f + W0_C * W0_C)) / (4.f * PI_F);
    const float s     = s0 * exp2f(0.125f * (float)sidx);
    const float inv_s = 1.f / s;

    const float2* yh1 = spec + (size_t)(b * 2 + 0) * N;
    const float2* yh2 = spec + (size_t)(b * 2 + 1) * N;

    // Morlet filter (w>0 one-sided), unit-energy norm, ifft 1/N folded in
    const float nrm   = PIM14 * sqrtf(TWOPI_F * s / DT_S) * (1.f / N);
    const float wstep = TWOPI_F / ((float)N * DT_S);

    float fm[8];
    float2 w1[8];
    #pragma unroll
    for (int i = 0; i < 8; ++i) {
        int   k = tid + i * NT;
        float f = 0.f;
        if (k >= 1 && k < N / 2) {
            float arg = s * (wstep * (float)k) - W0_C;
            f = nrm * expf(-0.5f * arg * arg);
        }
        fm[i] = f;
        float2 a = yh1[k];
        w1[i] = make_float2(a.x * f, a.y * f);
    }
    fft2048_reg<+1>(w1, A, B, tid);        // W1 in regs

    float2 w2[8];
    #pragma unroll
    for (int i = 0; i < 8; ++i) {
        int k = tid + i * NT;
        float2 c = yh2[k];
        w2[i] = make_float2(c.x * fm[i], c.y * fm[i]);
    }
    fft2048_reg<+1>(w2, A, B, tid);        // W2 in regs

    // pointwise products entirely in registers
    float2 P[8], C[8];
    #pragma unroll
    for (int i = 0; i < 8; ++i) {
        float2 a = w1[i], c = w2[i];
        P[i] = make_float2((a.x * a.x + a.y * a.y) * inv_s,
                           (c.x * c.x + c.y * c.y) * inv_s);
        C[i] = make_float2((a.x * c.x + a.y * c.y) * inv_s,
                           (a.y * c.x - a.x * c.y) * inv_s);
    }

    // Gaussian time-smoothing in Fourier domain (1/N folded into F)
    const float sdt = s / DT_S;
    const float fc  = -0.5f * sdt * sdt * (TWOPI_F / (float)N) * (TWOPI_F / (float)N);

    fft2048_reg<-1>(P, A, B, tid);
    #pragma unroll
    for (int i = 0; i < 8; ++i) {
        int   k  = tid + i * NT;
        int   mk = min(k, N - k);
        float F  = expf(fc * (float)(mk * mk)) * (1.f / N);
        P[i].x *= F; P[i].y *= F;
    }
    fft2048_reg<+1>(P, A, B, tid);         // Psm in regs

    fft2048_reg<-1>(C, A, B, tid);
    #pragma unroll
    for (int i = 0; i < 8; ++i) {
        int   k  = tid + i * NT;
        int   mk = min(k, N - k);
        float F  = expf(fc * (float)(mk * mk)) * (1.f / N);
        C[i].x *= F; C[i].y *= F;
    }
    fft2048_reg<+1>(C, A, B, tid);         // Csm in regs

    float4* To = T + ((size_t)bl * NSC + sidx) * N;
    #pragma unroll
    for (int i = 0; i < 8; ++i) {
        int k = tid + i * NT;
        To[k] = make_float4(P[i].x, P[i].y, C[i].x, C[i].y);
    }
}

// ---------------- K3: scale-axis boxcar conv + coherence + scale sum --------
__global__ __launch_bounds__(NT) void k_coh(const float4* __restrict__ T,
                                            float* __restrict__ coh, int b0) {
    const int bl = blockIdx.x >> 3;
    const int t  = ((blockIdx.x & 7) << 8) + threadIdx.x;
    const int b  = b0 + bl;
    const float4* col = T + (size_t)bl * NSC * N + t;

    float4 q[10];
    #pragma unroll
    for (int i = 0; i < 10; ++i) q[i] = make_float4(0.f, 0.f, 0.f, 0.f);
    #pragma unroll
    for (int i = 0; i < 5; ++i) q[5 + i] = col[(size_t)i * N];

    float acc = 0.f;
    const float w9 = 1.f / 9.f;
    for (int i = 0; i < NSC; ++i) {
        float sx = 0.f, sy = 0.f, sz = 0.f, sw = 0.f;
        #pragma unroll
        for (int k = 0; k < 10; ++k) { sx += q[k].x; sy += q[k].y; sz += q[k].z; sw += q[k].w; }
        float s1 = (sx - 0.5f * (q[0].x + q[9].x)) * w9;
        float s2 = (sy - 0.5f * (q[0].y + q[9].y)) * w9;
        float sr = (sz - 0.5f * (q[0].z + q[9].z)) * w9;
        float si = (sw - 0.5f * (q[0].w + q[9].w)) * w9;
        acc += (sr * sr + si * si) / (s1 * s2);
        #pragma unroll
        for (int k = 0; k < 9; ++k) q[k] = q[k + 1];
        int c = i + 5;
        q[9] = (c < NSC) ? col[(size_t)c * N] : make_float4(0.f, 0.f, 0.f, 0.f);
    }
    coh[(size_t)b * N + t] = acc;
}

// ---------------- K4: sliding-window sum over time ----------------
__global__ __launch_bounds__(NT) void k_win(const float* __restrict__ coh,
                                            float* __restrict__ out) {
    __shared__ float row[N];
    const int b   = blockIdx.x;
    const int tid = threadIdx.x;
    for (int i = tid; i < N; i += NT) row[i] = coh[(size_t)b * N + i];
    __syncthreads();
    for (int t0 = tid; t0 < NOUT; t0 += NT) {
        float ssum = 0.f;
        for (int k = 0; k < WS_WIN; ++k) ssum += row[t0 + k];
        out[(size_t)b * NOUT + t0] = ssum;
    }
}

// ---------------- host launcher ----------------
extern "C" void kernel_launch(void* const* d_in, const int* in_sizes, int n_in,
                              void* d_out, int out_size, void* d_ws, size_t ws_size,
                              hipStream_t stream) {
    const float* x   = (const float*)d_in[0];
    float*       out = (float*)d_out;
    char*        ws  = (char*)d_ws;

    const size_t spec_bytes = (size_t)BATCH * 2 * N * sizeof(float2); // 2 MB
    const size_t coh_bytes  = (size_t)BATCH * N * sizeof(float);      // 512 KB
    const size_t perBatchT  = (size_t)NSC * N * sizeof(float4);       // ~2.65 MB

    float2* spec = (float2*)ws;
    float*  coh  = (float*)(ws + spec_bytes);
    float4* T    = (float4*)(ws + spec_bytes + coh_bytes);

    size_t avail = (ws_size > spec_bytes + coh_bytes) ? (ws_size - spec_bytes - coh_bytes) : 0;
    int chunk = (int)(avail / perBatchT);
    if (chunk < 1) chunk = 1;
    if (chunk > BATCH) chunk = BATCH;

    k_fft_in<<<BATCH * 2, NT, 0, stream>>>(x, spec);
    for (int b0 = 0; b0 < BATCH; b0 += chunk) {
        int cb = BATCH - b0 < chunk ? BATCH - b0 : chunk;
        k_wct<<<cb * NSC, NT, 0, stream>>>(spec, T, b0);
        k_coh<<<cb * 8, NT, 0, stream>>>(T, coh, b0);
    }
    k_win<<<BATCH, NT, 0, stream>>>(coh, out);
}

// Round 4
// 202.080 us; speedup vs baseline: 1.3908x; 1.3908x over previous
//
#include <hip/hip_runtime.h>
#include <math.h>

// ---------------- problem constants ----------------
#define N        2048
#define NT       256      // threads per block
#define NSC      81       // number of scales (J+1)
#define BATCH    64
#define WS_WIN   94       // sliding window = 32*3-2
#define NOUT     1955     // N - WS_WIN + 1
#define DT_S     0.1f
#define W0_C     6.0f
#define PI_F     3.14159265358979f
#define TWOPI_F  6.28318530717959f
#define PIM14    0.7511255444649425f   // pi^(-1/4)
#define C_SQ2H   0.70710678118654752f  // sqrt(2)/2

// pad-swizzle: +1 element every 16 keeps every stage's b64 pattern at the
// 4-lane/bank-pair bandwidth floor
#define SWZ(e)   ((e) + ((e) >> 4))
#define LDSN     2176     // 2048 + 128 pad elements

__device__ __forceinline__ float2 cadd2(float2 a, float2 b) { return make_float2(a.x + b.x, a.y + b.y); }
__device__ __forceinline__ float2 csub2(float2 a, float2 b) { return make_float2(a.x - b.x, a.y - b.y); }
__device__ __forceinline__ float2 cmul2(float2 a, float2 b) { return make_float2(a.x * b.x - a.y * b.y, a.x * b.y + a.y * b.x); }

// 8-point DFT, natural-order outputs (sign SGN)
template<int SGN>
__device__ __forceinline__ void dft8(const float2 (&x)[8], float2 (&y)[8]) {
    const float s = (float)SGN;
    float2 t0 = cadd2(x[0], x[4]), t1 = cadd2(x[1], x[5]);
    float2 t2 = cadd2(x[2], x[6]), t3 = cadd2(x[3], x[7]);
    float2 u0 = csub2(x[0], x[4]);
    float2 d1 = csub2(x[1], x[5]);
    float2 d2 = csub2(x[2], x[6]);
    float2 d3 = csub2(x[3], x[7]);
    float2 u1 = make_float2(C_SQ2H * (d1.x - s * d1.y), C_SQ2H * (d1.y + s * d1.x));
    float2 u2 = make_float2(-s * d2.y, s * d2.x);
    float2 u3 = make_float2(-C_SQ2H * (d3.x + s * d3.y), C_SQ2H * (s * d3.x - d3.y));
    float2 a0 = cadd2(t0, t2), a1 = cadd2(t1, t3), b0 = csub2(t0, t2), e1 = csub2(t1, t3);
    float2 b1 = make_float2(-s * e1.y, s * e1.x);
    y[0] = cadd2(a0, a1); y[4] = csub2(a0, a1); y[2] = cadd2(b0, b1); y[6] = csub2(b0, b1);
    float2 c0 = cadd2(u0, u2), c1 = cadd2(u1, u3), g0 = csub2(u0, u2), h1 = csub2(u1, u3);
    float2 g1 = make_float2(-s * h1.y, s * h1.x);
    y[1] = cadd2(c0, c1); y[5] = csub2(c0, c1); y[3] = cadd2(g0, g1); y[7] = csub2(g0, g1);
}

// twiddle by w^u (w = exp(SGN*2pi*i*jm/N)) and scatter-store
template<int SGN>
__device__ __forceinline__ void twiddle_store(const float2 (&y)[8], float2* __restrict__ dst,
                                              int jm, int base, int m) {
    float ang = (float)SGN * (TWOPI_F / (float)N) * (float)jm;
    float sn, cs; __sincosf(ang, &sn, &cs);
    float2 w1 = make_float2(cs, sn);
    float2 w2 = cmul2(w1, w1);
    float2 w3 = cmul2(w2, w1);
    float2 w4 = cmul2(w2, w2);
    float2 w5 = cmul2(w3, w2);
    float2 w6 = cmul2(w3, w3);
    float2 w7 = cmul2(w4, w3);
    dst[SWZ(base)]         = y[0];
    dst[SWZ(base + m)]     = cmul2(y[1], w1);
    dst[SWZ(base + 2 * m)] = cmul2(y[2], w2);
    dst[SWZ(base + 3 * m)] = cmul2(y[3], w3);
    dst[SWZ(base + 4 * m)] = cmul2(y[4], w4);
    dst[SWZ(base + 5 * m)] = cmul2(y[5], w5);
    dst[SWZ(base + 6 * m)] = cmul2(y[6], w6);
    dst[SWZ(base + 7 * m)] = cmul2(y[7], w7);
}

// stage 1 (m=1): input from registers x[p] = element tid + p*256
template<int SGN>
__device__ __forceinline__ void stage1_reg(const float2 (&x)[8], float2* __restrict__ dst, int tid) {
    float2 y[8];
    dft8<SGN>(x, y);
    twiddle_store<SGN>(y, dst, tid, 8 * tid, 1);
}

// middle radix-8 stage, LDS -> LDS
template<int SGN>
__device__ __forceinline__ void stage8_lds(const float2* __restrict__ src,
                                           float2* __restrict__ dst, int q, int shift) {
    float2 xin[8];
    #pragma unroll
    for (int p = 0; p < 8; ++p) xin[p] = src[SWZ(q + p * 256)];
    float2 y[8];
    dft8<SGN>(xin, y);
    const int m  = 1 << shift;
    const int jm = q & ~(m - 1);
    twiddle_store<SGN>(y, dst, jm, q + 7 * jm, m);
}

// final radix-4 stage (m=512, j=0, no twiddles): outputs land back in regs,
// x[2u+qq] = element tid + (2u+qq)*256  (natural order, thread-owned)
template<int SGN>
__device__ __forceinline__ void stage4_regs(const float2* __restrict__ src, float2 (&x)[8], int tid) {
    const float s = (float)SGN;
    #pragma unroll
    for (int qq = 0; qq < 2; ++qq) {
        int q = tid + qq * 256;
        float2 x0 = src[SWZ(q)];
        float2 x1 = src[SWZ(q + 512)];
        float2 x2 = src[SWZ(q + 1024)];
        float2 x3 = src[SWZ(q + 1536)];
        float2 a0 = cadd2(x0, x2), a1 = cadd2(x1, x3);
        float2 b0 = csub2(x0, x2), e1 = csub2(x1, x3);
        float2 b1 = make_float2(-s * e1.y, s * e1.x);
        x[0 + qq] = cadd2(a0, a1);
        x[2 + qq] = cadd2(b0, b1);
        x[4 + qq] = csub2(a0, a1);
        x[6 + qq] = csub2(b0, b1);
    }
}

// full 2048-pt FFT, register in / register out (x[i] = element tid + i*256).
// SGN=-1: forward (numpy fft). SGN=+1: inverse exponent (1/N not applied).
template<int SGN>
__device__ __forceinline__ void fft2048_reg(float2 (&x)[8], float2* A, float2* B, int tid) {
    __syncthreads();                     // protect B from previous FFT's reads
    stage1_reg<SGN>(x, B, tid);          // regs -> B   (m=1)
    __syncthreads();
    stage8_lds<SGN>(B, A, tid, 3);       // B -> A      (m=8)
    __syncthreads();
    stage8_lds<SGN>(A, B, tid, 6);       // A -> B      (m=64)
    __syncthreads();
    stage4_regs<SGN>(B, x, tid);         // B -> regs   (m=512)
}

// ---------------- K1: normalize + forward FFT of each signal ----------------
__global__ __launch_bounds__(NT) void k_fft_in(const float* __restrict__ x,
                                               float2* __restrict__ spec) {
    __shared__ float2 A[LDSN];
    __shared__ float2 B[LDSN];
    __shared__ float  rs[NT], rq[NT];
    const int    tid = threadIdx.x;
    const float* y   = x + (size_t)blockIdx.x * N;

    float v[8];
    float lsum = 0.f, lsq = 0.f;
    #pragma unroll
    for (int i = 0; i < 8; ++i) {
        float t = y[tid + i * NT];
        v[i] = t; lsum += t; lsq += t * t;
    }
    rs[tid] = lsum; rq[tid] = lsq;
    __syncthreads();
    for (int o = NT / 2; o > 0; o >>= 1) {
        if (tid < o) { rs[tid] += rs[tid + o]; rq[tid] += rq[tid + o]; }
        __syncthreads();
    }
    const float mean = rs[0] * (1.f / N);
    const float var  = rq[0] * (1.f / N) - mean * mean;
    const float inv  = rsqrtf(var);

    float2 z[8];
    #pragma unroll
    for (int i = 0; i < 8; ++i) z[i] = make_float2((v[i] - mean) * inv, 0.f);

    fft2048_reg<-1>(z, A, B, tid);

    float2* o2 = spec + (size_t)blockIdx.x * N;
    #pragma unroll
    for (int i = 0; i < 8; ++i) o2[tid + i * NT] = z[i];
}

// ---------------- K2: per (batch, scale) CWT + smoothing ----------------
// launch_bounds(256,3): VGPR cap ~170 -> guaranteed no scratch spill (R3's
// (256,4) clamped to 64 VGPRs and spilled ~640 MB of scratch traffic).
// LDS 2x17KB still allows 4 blocks/CU if compiler lands <=128 VGPRs.
__global__ __launch_bounds__(NT, 3) void k_wct(const float2* __restrict__ spec,
                                               float4* __restrict__ T, int b0) {
    __shared__ float2 A[LDSN];
    __shared__ float2 B[LDSN];
    const int tid  = threadIdx.x;
    const int sidx = blockIdx.x % NSC;
    const int bl   = blockIdx.x / NSC;
    const int b    = b0 + bl;

    const float s0    = 2.f * DT_S * (W0_C + sqrtf(2.f + W0_C * W0_C)) / (4.f * PI_F);
    const float s     = s0 * exp2f(0.125f * (float)sidx);
    const float inv_s = 1.f / s;

    const float2* yh1 = spec + (size_t)(b * 2 + 0) * N;
    const float2* yh2 = spec + (size_t)(b * 2 + 1) * N;

    // Morlet filter (w>0 one-sided), unit-energy norm, ifft 1/N folded in
    const float nrm   = PIM14 * sqrtf(TWOPI_F * s / DT_S) * (1.f / N);
    const float wstep = TWOPI_F / ((float)N * DT_S);

    float fm[8];
    float2 w1[8];
    #pragma unroll
    for (int i = 0; i < 8; ++i) {
        int   k = tid + i * NT;
        float f = 0.f;
        if (k >= 1 && k < N / 2) {
            float arg = s * (wstep * (float)k) - W0_C;
            f = nrm * expf(-0.5f * arg * arg);
        }
        fm[i] = f;
        float2 a = yh1[k];
        w1[i] = make_float2(a.x * f, a.y * f);
    }
    fft2048_reg<+1>(w1, A, B, tid);        // W1 in regs

    float2 w2[8];
    #pragma unroll
    for (int i = 0; i < 8; ++i) {
        int k = tid + i * NT;
        float2 c = yh2[k];
        w2[i] = make_float2(c.x * fm[i], c.y * fm[i]);
    }
    fft2048_reg<+1>(w2, A, B, tid);        // W2 in regs

    // pointwise products entirely in registers
    float2 P[8], C[8];
    #pragma unroll
    for (int i = 0; i < 8; ++i) {
        float2 a = w1[i], c = w2[i];
        P[i] = make_float2((a.x * a.x + a.y * a.y) * inv_s,
                           (c.x * c.x + c.y * c.y) * inv_s);
        C[i] = make_float2((a.x * c.x + a.y * c.y) * inv_s,
                           (a.y * c.x - a.x * c.y) * inv_s);
    }

    // Gaussian time-smoothing in Fourier domain (1/N folded into F)
    const float sdt = s / DT_S;
    const float fc  = -0.5f * sdt * sdt * (TWOPI_F / (float)N) * (TWOPI_F / (float)N);

    fft2048_reg<-1>(P, A, B, tid);
    #pragma unroll
    for (int i = 0; i < 8; ++i) {
        int   k  = tid + i * NT;
        int   mk = min(k, N - k);
        float F  = expf(fc * (float)(mk * mk)) * (1.f / N);
        P[i].x *= F; P[i].y *= F;
    }
    fft2048_reg<+1>(P, A, B, tid);         // Psm in regs

    fft2048_reg<-1>(C, A, B, tid);
    #pragma unroll
    for (int i = 0; i < 8; ++i) {
        int   k  = tid + i * NT;
        int   mk = min(k, N - k);
        float F  = expf(fc * (float)(mk * mk)) * (1.f / N);
        C[i].x *= F; C[i].y *= F;
    }
    fft2048_reg<+1>(C, A, B, tid);         // Csm in regs

    float4* To = T + ((size_t)bl * NSC + sidx) * N;
    #pragma unroll
    for (int i = 0; i < 8; ++i) {
        int k = tid + i * NT;
        To[k] = make_float4(P[i].x, P[i].y, C[i].x, C[i].y);
    }
}

// ---------------- K3: scale-axis boxcar conv + coherence + scale sum --------
__global__ __launch_bounds__(NT) void k_coh(const float4* __restrict__ T,
                                            float* __restrict__ coh, int b0) {
    const int bl = blockIdx.x >> 3;
    const int t  = ((blockIdx.x & 7) << 8) + threadIdx.x;
    const int b  = b0 + bl;
    const float4* col = T + (size_t)bl * NSC * N + t;

    float4 q[10];
    #pragma unroll
    for (int i = 0; i < 10; ++i) q[i] = make_float4(0.f, 0.f, 0.f, 0.f);
    #pragma unroll
    for (int i = 0; i < 5; ++i) q[5 + i] = col[(size_t)i * N];

    float acc = 0.f;
    const float w9 = 1.f / 9.f;
    for (int i = 0; i < NSC; ++i) {
        float sx = 0.f, sy = 0.f, sz = 0.f, sw = 0.f;
        #pragma unroll
        for (int k = 0; k < 10; ++k) { sx += q[k].x; sy += q[k].y; sz += q[k].z; sw += q[k].w; }
        float s1 = (sx - 0.5f * (q[0].x + q[9].x)) * w9;
        float s2 = (sy - 0.5f * (q[0].y + q[9].y)) * w9;
        float sr = (sz - 0.5f * (q[0].z + q[9].z)) * w9;
        float si = (sw - 0.5f * (q[0].w + q[9].w)) * w9;
        acc += (sr * sr + si * si) / (s1 * s2);
        #pragma unroll
        for (int k = 0; k < 9; ++k) q[k] = q[k + 1];
        int c = i + 5;
        q[9] = (c < NSC) ? col[(size_t)c * N] : make_float4(0.f, 0.f, 0.f, 0.f);
    }
    coh[(size_t)b * N + t] = acc;
}

// ---------------- K4: sliding-window sum over time ----------------
__global__ __launch_bounds__(NT) void k_win(const float* __restrict__ coh,
                                            float* __restrict__ out) {
    __shared__ float row[N];
    const int b   = blockIdx.x;
    const int tid = threadIdx.x;
    for (int i = tid; i < N; i += NT) row[i] = coh[(size_t)b * N + i];
    __syncthreads();
    for (int t0 = tid; t0 < NOUT; t0 += NT) {
        float ssum = 0.f;
        for (int k = 0; k < WS_WIN; ++k) ssum += row[t0 + k];
        out[(size_t)b * NOUT + t0] = ssum;
    }
}

// ---------------- host launcher ----------------
extern "C" void kernel_launch(void* const* d_in, const int* in_sizes, int n_in,
                              void* d_out, int out_size, void* d_ws, size_t ws_size,
                              hipStream_t stream) {
    const float* x   = (const float*)d_in[0];
    float*       out = (float*)d_out;
    char*        ws  = (char*)d_ws;

    const size_t spec_bytes = (size_t)BATCH * 2 * N * sizeof(float2); // 2 MB
    const size_t coh_bytes  = (size_t)BATCH * N * sizeof(float);      // 512 KB
    const size_t perBatchT  = (size_t)NSC * N * sizeof(float4);       // ~2.65 MB

    float2* spec = (float2*)ws;
    float*  coh  = (float*)(ws + spec_bytes);
    float4* T    = (float4*)(ws + spec_bytes + coh_bytes);

    size_t avail = (ws_size > spec_bytes + coh_bytes) ? (ws_size - spec_bytes - coh_bytes) : 0;
    int chunk = (int)(avail / perBatchT);
    if (chunk < 1) chunk = 1;
    if (chunk > BATCH) chunk = BATCH;

    k_fft_in<<<BATCH * 2, NT, 0, stream>>>(x, spec);
    for (int b0 = 0; b0 < BATCH; b0 += chunk) {
        int cb = BATCH - b0 < chunk ? BATCH - b0 : chunk;
        k_wct<<<cb * NSC, NT, 0, stream>>>(spec, T, b0);
        k_coh<<<cb * 8, NT, 0, stream>>>(T, coh, b0);
    }
    k_win<<<BATCH, NT, 0, stream>>>(coh, out);
}